// Round 13
// baseline (201.259 us; speedup 1.0000x reference)
//
#include <hip/hip_runtime.h>
#include <math.h>

#define NN 512
#define BB 16
#define TOTAL (BB * NN * NN)   // 4,194,304 cells
#define EPS_F 1e-5f
#define DELTA_F 0.05f

#define HALO 8
#define TILE 64                 // tile (64 rows x 64 cols), output 48x48
#define OUT  48
#define RPW  16                 // rows per wave (4 waves x 16 = 64 rows)
#define GUARD 16384             // bytes; halo over/under-run is <= ~8.5 KB

// bf16 helpers (storage only; all math in f32)
__device__ __forceinline__ float bf16_ld(unsigned short h) {
    return __uint_as_float((unsigned)h << 16);
}
__device__ __forceinline__ unsigned short bf16_st(float f) {
    unsigned b = __float_as_uint(f);
    return (unsigned short)((b + 0x7FFFu + ((b >> 16) & 1u)) >> 16);  // RNE
}

// whole-wave lane shifts (gfx9-lineage DPP). Direction labels per row_shr
// convention; note the stencil uses lf+rt as a SYMMETRIC sum and bound_ctrl
// zeros land on frozen ring columns, so either direction assignment yields
// identical results.
__device__ __forceinline__ float wshr1(float x) {   // lane i <- lane i-1; lane0 -> 0
    int r = __builtin_amdgcn_update_dpp(0, __float_as_int(x), 0x138, 0xf, 0xf, true);
    return __int_as_float(r);
}
__device__ __forceinline__ float wshl1(float x) {   // lane i <- lane i+1; lane63 -> 0
    int r = __builtin_amdgcn_update_dpp(0, __float_as_int(x), 0x130, 0xf, 0xf, true);
    return __int_as_float(r);
}

// ---------------------------------------------------------------------------
// Init (4 cells/thread, vectorized): u0(bf16) = dir ? bc : 0 ;
// cmask(u8) = fluid ; pre(bf16) = w_outer * [geom<=0.5] * (x·w_back + b)
// ---------------------------------------------------------------------------
__global__ __launch_bounds__(256) void init_kernel(
    const float4* __restrict__ xm4,
    unsigned short* __restrict__ u,
    unsigned char* __restrict__ cmask,
    unsigned short* __restrict__ pre,
    const float* __restrict__ w_back,
    const float* __restrict__ b_back)
{
    int g = blockIdx.x * 256 + threadIdx.x;      // 0 .. TOTAL/4-1
    int idx = g * 4;
    int j0 = idx & (NN - 1);
    int i  = (idx >> 9) & (NN - 1);
    float w0 = w_back[0], w1 = w_back[1], bb0 = b_back[0];
    float xs = (float)i * (1.0f / 511.0f);
    float dx = fminf(xs, 1.0f - xs);
    bool iedge = (i == 0) | (i == NN - 1);

    unsigned uw[2] = {0u, 0u};
    unsigned mw = 0u;
    unsigned pw[2] = {0u, 0u};
#pragma unroll
    for (int c = 0; c < 4; ++c) {
        float4 xm = xm4[idx + c];
        int j = j0 + c;
        bool dir = iedge | (j == 0) | (j == NN - 1) | (xm.z > 0.5f);
        unsigned us = bf16_st(dir ? xm.w : 0.0f);
        uw[c >> 1] |= us << ((c & 1) * 16);
        mw |= (dir ? 0u : 1u) << (c * 8);

        float rr = xm.x * w0 + xm.y * w1 + bb0;
        float ys = (float)j * (1.0f / 511.0f);
        float dd = fminf(dx, fminf(ys, 1.0f - ys));
        float ww = fminf(fmaxf(dd * (1.0f / DELTA_F), 0.0f), 1.0f);
        if (xm.z > 0.5f) ww = 0.0f;
        unsigned ps = bf16_st(ww * rr);
        pw[c >> 1] |= ps << ((c & 1) * 16);
    }
    *(uint2*)(u + idx)        = make_uint2(uw[0], uw[1]);
    *(unsigned*)(cmask + idx) = mw;
    *(uint2*)(pre + idx)      = make_uint2(pw[0], pw[1]);
}

// ---------------------------------------------------------------------------
// Lane-major register-tile stencil: lane = tile column (64), wave = 16-row
// band (4 waves = 64 rows). Each thread owns a 16-deep column strip in
// registers. Vertical neighbors: in-register (u[r+-1]); band boundaries:
// 2 LDS writes + 2 reads + 1 barrier per iteration (double-buffered).
// Horizontal neighbors: whole-wave DPP lane shifts (fused into v_add).
// Ring cells frozen (cf=0) annihilate garbage halo values via fma; guarded
// OOB reads only ever see finite values behind the frozen global edge.
// ---------------------------------------------------------------------------
template<int ITERS, bool FINAL>
__global__ __launch_bounds__(256, 8) void stencil_kernel(
    const unsigned short* __restrict__ uin,
    unsigned short* __restrict__ uout,      // bf16 dest (non-final)
    float* __restrict__ fout,               // f32 dest (final)
    const unsigned char* __restrict__ cmask,
    const unsigned short* __restrict__ pre,
    const float* __restrict__ logit,
    const float* __restrict__ y_mean,
    const float* __restrict__ y_std)
{
    __shared__ float xtop[2][256];   // each thread's u[0]      (read by band below)
    __shared__ float xbot[2][256];   // each thread's u[RPW-1]  (read by band above)

    const int b   = blockIdx.z;
    const int oy  = min((int)blockIdx.y * OUT, NN - OUT);
    const int ox  = min((int)blockIdx.x * OUT, NN - OUT);
    const int tid = threadIdx.x;
    const int w   = tid >> 6;          // wave 0..3  (row band)
    const int l   = tid & 63;          // lane = tile column
    const int rb  = w * RPW;           // tile row base of this band

    const size_t slab = (size_t)b * NN * NN;
    const unsigned short* ub = uin + slab;
    const unsigned char*  cb = cmask + slab;

    float u[RPW];
    float cf[RPW];   // 1.0 = fluid (update), 0.0 = Dirichlet/frozen

    // ---- setup: per row, 64 lanes load contiguous u16/u8 (coalesced) ----
    const int gx = ox - HALO + l;
#pragma unroll
    for (int r = 0; r < RPW; ++r) {
        int ty  = rb + r;
        int gy  = oy - HALO + ty;
        int off = gy * NN + gx;            // may stray into guard: finite
        u[r] = bf16_ld(ub[off]);
        unsigned m = cb[off];
        bool ring = (ty == 0) | (ty == TILE - 1) | (l == 0) | (l == 63);
        cf[r] = (ring || m == 0u) ? 0.0f : 1.0f;
    }

    const int iup = (w > 0) ? tid - 64 : tid;   // clamped: w=0 garbage killed by ring
    const int idn = (w < 3) ? tid + 64 : tid;   // clamped: w=3 garbage killed by ring

    // ---- ITERS fused Jacobi iterations ----
#pragma unroll 1
    for (int t = 0; t < ITERS; ++t) {
        const int pb = t & 1;
        xtop[pb][tid] = u[0];
        xbot[pb][tid] = u[RPW - 1];
        __syncthreads();
        float pu = xbot[pb][iup];   // old row above band (tile row rb-1)
        float bh = xtop[pb][idn];   // old row below band (tile row rb+RPW)
#pragma unroll
        for (int r = 0; r < RPW; ++r) {
            float od = u[r];
            float dn = (r < RPW - 1) ? u[r + 1] : bh;
            float s  = pu + dn;
            s += wshr1(od);          // left neighbor (lane-1), fused add_dpp
            s += wshl1(od);          // right neighbor (lane+1)
            float tq = __builtin_fmaf(0.25f, s, -od);
            u[r] = __builtin_fmaf(cf[r], tq, od);
            pu = od;
        }
    }

    // ---- store center 48x48 (rows with rb+r in [8,56), cols l in [8,56)) ----
    const bool lok = (l >= HALO) & (l < TILE - HALO);
    if (!FINAL) {
        if (lok) {
            unsigned short* og = uout + slab;
            int gcol = ox - HALO + l;
#pragma unroll
            for (int r = 0; r < RPW; ++r) {
                int ty = rb + r;
                if ((ty >= HALO) & (ty < TILE - HALO)) {
                    int grow = oy - HALO + ty;
                    og[grow * NN + gcol] = bf16_st(u[r]);
                }
            }
        }
    } else {
        if (lok) {
            float* og = fout + slab;
            const unsigned short* pg = pre + slab;
            float rs  = 0.25f / (1.0f + expf(-logit[0]));
            float ym  = y_mean[0];
            float inv = 1.0f / (y_std[0] + EPS_F);
            int gcol = ox - HALO + l;
#pragma unroll
            for (int r = 0; r < RPW; ++r) {
                int ty = rb + r;
                if ((ty >= HALO) & (ty < TILE - HALO)) {
                    int grow = oy - HALO + ty;
                    float e = (u[r] - ym) * inv;
                    float p = bf16_ld(pg[grow * NN + gcol]);
                    og[grow * NN + gcol] = __builtin_fmaf(rs, p, e);
                }
            }
        }
    }
}

// ---------------------------------------------------------------------------
extern "C" void kernel_launch(void* const* d_in, const int* in_sizes, int n_in,
                              void* d_out, int out_size, void* d_ws, size_t ws_size,
                              hipStream_t stream)
{
    const float* x_mix  = (const float*)d_in[0];
    const float* w_back = (const float*)d_in[1];
    const float* b_back = (const float*)d_in[2];
    const float* logit  = (const float*)d_in[3];
    const float* y_mean = (const float*)d_in[4];
    const float* y_std  = (const float*)d_in[5];

    float* out = (float*)d_out;

    // Workspace: [GUARD][u_a 2B][cmask 1B][u_b 2B][pre 2B] — halo reads may
    // stray up to ~8.5 KB past either end of u_a/u_b/cmask; every such access
    // lands in an adjacent defined region or the guard, all finite when
    // decoded, and garbage cannot cross the frozen global-edge rows/cols.
    char* ws = (char*)d_ws;
    unsigned short* u_a   = (unsigned short*)(ws + GUARD);
    unsigned char*  cmask = (unsigned char*) (ws + GUARD + (size_t)TOTAL * 2);
    unsigned short* u_b   = (unsigned short*)(ws + GUARD + (size_t)TOTAL * 3);
    unsigned short* pre   = (unsigned short*)(ws + GUARD + (size_t)TOTAL * 5);

    init_kernel<<<TOTAL / 4 / 256, 256, 0, stream>>>(
        (const float4*)x_mix, u_a, cmask, pre, w_back, b_back);

    // 50 iters = 6 launches x 8 + 1 launch x 2 (fused epilogue).
    // Chain: a->b, b->a, a->b, b->a, a->b, b->a, then FINAL a->out.
    dim3 sgrid((NN + OUT - 1) / OUT, (NN + OUT - 1) / OUT, BB);  // 11x11x16
    stencil_kernel<8, false><<<sgrid, 256, 0, stream>>>(u_a, u_b, out, cmask,
        pre, logit, y_mean, y_std);
    stencil_kernel<8, false><<<sgrid, 256, 0, stream>>>(u_b, u_a, out, cmask,
        pre, logit, y_mean, y_std);
    stencil_kernel<8, false><<<sgrid, 256, 0, stream>>>(u_a, u_b, out, cmask,
        pre, logit, y_mean, y_std);
    stencil_kernel<8, false><<<sgrid, 256, 0, stream>>>(u_b, u_a, out, cmask,
        pre, logit, y_mean, y_std);
    stencil_kernel<8, false><<<sgrid, 256, 0, stream>>>(u_a, u_b, out, cmask,
        pre, logit, y_mean, y_std);
    stencil_kernel<8, false><<<sgrid, 256, 0, stream>>>(u_b, u_a, out, cmask,
        pre, logit, y_mean, y_std);
    stencil_kernel<2, true><<<sgrid, 256, 0, stream>>>(u_a, u_b, out, cmask,
        pre, logit, y_mean, y_std);
}

// Round 14
// 147.286 us; speedup vs baseline: 1.3665x; 1.3665x over previous
//
#include <hip/hip_runtime.h>
#include <math.h>

#define NN 512
#define BB 16
#define TOTAL (BB * NN * NN)   // 4,194,304 cells
#define EPS_F 1e-5f
#define DELTA_F 0.05f

#define HALO 8
#define TDIM 64                 // tile: 64 cols (lanes) x 64 rows (registers)
#define OUTT 48                 // valid center 48x48
#define NT   11                 // tiles per dim (11*48=528 covers 512 w/ overlap)
#define NTILES (NT * NT * BB)   // 1936 wave-tiles
#define GUARD 16384

// bf16 helpers (storage only; all math in f32)
__device__ __forceinline__ float bf16_lo(unsigned v) { return __uint_as_float(v << 16); }
__device__ __forceinline__ float bf16_hi(unsigned v) { return __uint_as_float(v & 0xFFFF0000u); }
__device__ __forceinline__ unsigned short bf16_st(float f) {
    unsigned b = __float_as_uint(f);
    return (unsigned short)((b + 0x7FFFu + ((b >> 16) & 1u)) >> 16);  // RNE
}

// whole-wave lane shifts (DPP; bound_ctrl zeros land on frozen ring columns,
// and the stencil sum lf+rt is symmetric, so direction naming is immaterial)
__device__ __forceinline__ float wshr1(float x) {
    int r = __builtin_amdgcn_update_dpp(0, __float_as_int(x), 0x138, 0xf, 0xf, true);
    return __int_as_float(r);
}
__device__ __forceinline__ float wshl1(float x) {
    int r = __builtin_amdgcn_update_dpp(0, __float_as_int(x), 0x130, 0xf, 0xf, true);
    return __int_as_float(r);
}

// ---------------------------------------------------------------------------
// Init: read x_mix row-major; write u0 / cmask / pre TRANSPOSED ([b][col][row])
// via LDS 64x64 tile transpose. u0(bf16)=dir?bc:0; cmask(u8)=fluid;
// pre(bf16)=w_outer*[geom<=0.5]*(x·w_back+b_back).
// ---------------------------------------------------------------------------
__global__ __launch_bounds__(256) void init_kernel(
    const float4* __restrict__ xm4,
    unsigned short* __restrict__ u_t,
    unsigned char* __restrict__ cm_t,
    unsigned short* __restrict__ pre_t,
    const float* __restrict__ w_back,
    const float* __restrict__ b_back)
{
    __shared__ unsigned short lu[64][65];
    __shared__ unsigned short lp[64][65];
    __shared__ unsigned char  lm[64][64];

    const int b  = blockIdx.z;
    const int i0 = blockIdx.y * 64;
    const int j0 = blockIdx.x * 64;
    const int tid = threadIdx.x;
    const int tr = tid >> 4, tc = tid & 15;
    const int R0 = tr * 4, C0 = tc * 4;

    float w0 = w_back[0], w1 = w_back[1], bb0 = b_back[0];

    // Phase A: compute 4x4 cells, stage row-major into LDS
#pragma unroll
    for (int r = 0; r < 4; ++r) {
        int i = i0 + R0 + r;
        float xs = (float)i * (1.0f / 511.0f);
        float dx = fminf(xs, 1.0f - xs);
        bool iedge = (i == 0) | (i == NN - 1);
#pragma unroll
        for (int c = 0; c < 4; ++c) {
            int j = j0 + C0 + c;
            float4 xm = xm4[(size_t)((b * NN + i) * NN + j)];
            bool dir = iedge | (j == 0) | (j == NN - 1) | (xm.z > 0.5f);
            lu[R0 + r][C0 + c] = bf16_st(dir ? xm.w : 0.0f);
            lm[R0 + r][C0 + c] = dir ? 0 : 1;

            float rr = xm.x * w0 + xm.y * w1 + bb0;
            float ys = (float)j * (1.0f / 511.0f);
            float dd = fminf(dx, fminf(ys, 1.0f - ys));
            float ww = fminf(fmaxf(dd * (1.0f / DELTA_F), 0.0f), 1.0f);
            if (xm.z > 0.5f) ww = 0.0f;
            lp[R0 + r][C0 + c] = bf16_st(ww * rr);
        }
    }
    __syncthreads();

    // Phase B: write transposed, vectorized (16 rows of one column / thread)
    const int cj = tid & 63;          // column within tile
    const int r0 = (tid >> 6) * 16;   // row chunk
    const size_t base = (size_t)b * NN * NN + (size_t)(j0 + cj) * NN + (i0 + r0);

    uint4 a, bq;
    unsigned* ap = (unsigned*)&a;
    unsigned* bp = (unsigned*)&bq;
#pragma unroll
    for (int k = 0; k < 4; ++k) {
        ap[k] = (unsigned)lu[r0 + 2*k][cj]     | ((unsigned)lu[r0 + 2*k + 1][cj] << 16);
        bp[k] = (unsigned)lu[r0 + 8 + 2*k][cj] | ((unsigned)lu[r0 + 9 + 2*k][cj] << 16);
    }
    *(uint4*)(u_t + base)     = a;
    *(uint4*)(u_t + base + 8) = bq;
#pragma unroll
    for (int k = 0; k < 4; ++k) {
        ap[k] = (unsigned)lp[r0 + 2*k][cj]     | ((unsigned)lp[r0 + 2*k + 1][cj] << 16);
        bp[k] = (unsigned)lp[r0 + 8 + 2*k][cj] | ((unsigned)lp[r0 + 9 + 2*k][cj] << 16);
    }
    *(uint4*)(pre_t + base)     = a;
    *(uint4*)(pre_t + base + 8) = bq;

    uint4 mm;
    unsigned* mp = (unsigned*)&mm;
#pragma unroll
    for (int k = 0; k < 4; ++k)
        mp[k] = (unsigned)lm[r0 + 4*k][cj]            | ((unsigned)lm[r0 + 4*k + 1][cj] << 8)
              | ((unsigned)lm[r0 + 4*k + 2][cj] << 16) | ((unsigned)lm[r0 + 4*k + 3][cj] << 24);
    *(uint4*)(cm_t + base) = mm;
}

// ---------------------------------------------------------------------------
// Wave-autonomous stencil on transposed state: ONE WAVE owns one 64x64 tile.
// lane = column (horizontal neighbors = whole-wave DPP), 64 rows in registers
// (vertical neighbors in-register). NO barriers, NO LDS. I/O is wide and
// contiguous thanks to the column-major layout. Ring (rows/cols 0,63 of the
// tile) frozen; garbage beyond the frozen global-edge rows/cols cannot cross
// them (5-point stencil), so guarded OOB reads are benign (all finite).
// ---------------------------------------------------------------------------
template<int ITERS, bool FINAL>
__global__ __launch_bounds__(256, 2) void wave_kernel(
    const unsigned short* __restrict__ uin,
    unsigned short* __restrict__ uout,      // bf16 dest (non-final)
    float* __restrict__ fout,               // f32 dest (final, row-major)
    const unsigned char* __restrict__ cm_t,
    const unsigned short* __restrict__ pre_t,
    const float* __restrict__ logit,
    const float* __restrict__ y_mean,
    const float* __restrict__ y_std)
{
    const int tid  = threadIdx.x;
    const int lane = tid & 63;
    int wid = blockIdx.x * 4 + (tid >> 6);          // 0 .. NTILES-1
    if (wid >= NTILES) return;
    int b   = wid / (NT * NT);
    int rem = wid - b * (NT * NT);
    int ty  = rem / NT;
    int tx  = rem - ty * NT;
    const int oy = min(ty * OUTT, NN - OUTT);       // valid rows oy..oy+47
    const int ox = min(tx * OUTT, NN - OUTT);       // valid cols ox..ox+47
    const int gy0 = oy - HALO;
    const int col = ox - HALO + lane;

    const size_t sbase = (size_t)b * NN * NN;
    const long   cbase = (long)col * NN + gy0;      // may be negative: guarded

    // ---- load 64 rows of my column: 8 x uint4 (u16x8 each) ----
    float u[TDIM];
    {
        const unsigned short* up = uin + sbase + cbase;
#pragma unroll
        for (int k = 0; k < 8; ++k) {
            uint4 v = *(const uint4*)(up + k * 8);
            const unsigned* vp = (const unsigned*)&v;
#pragma unroll
            for (int q = 0; q < 4; ++q) {
                u[k * 8 + 2*q]     = bf16_lo(vp[q]);
                u[k * 8 + 2*q + 1] = bf16_hi(vp[q]);
            }
        }
    }
    // ---- load 64 mask bytes: 8 x uint2 (8B-aligned), build cf ----
    float cf[TDIM];
    {
        const unsigned char* cp = cm_t + sbase + cbase;
        unsigned mwv[16];
#pragma unroll
        for (int k = 0; k < 8; ++k) {
            uint2 m = *(const uint2*)(cp + k * 8);
            mwv[2*k] = m.x; mwv[2*k+1] = m.y;
        }
        float lok = ((unsigned)(lane - 1) < 62u) ? 1.0f : 0.0f;  // lanes 1..62
#pragma unroll
        for (int r = 0; r < TDIM; ++r) {
            unsigned byte = (mwv[r >> 2] >> ((r & 3) * 8)) & 0xFFu;
            cf[r] = byte ? lok : 0.0f;
        }
        cf[0] = 0.0f; cf[TDIM - 1] = 0.0f;
    }

    // ---- ITERS Jacobi iterations, zero barriers / zero LDS ----
#pragma unroll 1
    for (int t = 0; t < ITERS; ++t) {
        float pu = u[0];
#pragma unroll
        for (int r = 1; r < TDIM - 1; ++r) {
            float od = u[r];
            float s  = pu + u[r + 1];
            s += wshr1(od);
            s += wshl1(od);
            float tq = __builtin_fmaf(0.25f, s, -od);
            u[r] = __builtin_fmaf(cf[r], tq, od);
            pu = od;
        }
    }

    // ---- store valid center ----
    const bool lok = (lane >= HALO) & (lane < TDIM - HALO);
    if (!FINAL) {
        if (lok) {
            unsigned short* op = uout + sbase + (size_t)col * NN + oy;
#pragma unroll
            for (int k = 0; k < 6; ++k) {
                uint4 v;
                unsigned* vp = (unsigned*)&v;
#pragma unroll
                for (int q = 0; q < 4; ++q) {
                    int r = HALO + k * 8 + 2*q;
                    vp[q] = (unsigned)bf16_st(u[r]) | ((unsigned)bf16_st(u[r + 1]) << 16);
                }
                *(uint4*)(op + k * 8) = v;
            }
        }
    } else {
        float rs  = 0.25f / (1.0f + expf(-logit[0]));
        float ym  = y_mean[0];
        float inv = 1.0f / (y_std[0] + EPS_F);
        float pr[OUTT];
        if (lok) {   // pre reads predicated: in-range columns only
            const unsigned short* pp = pre_t + sbase + (size_t)col * NN + oy;
#pragma unroll
            for (int k = 0; k < 6; ++k) {
                uint4 v = *(const uint4*)(pp + k * 8);
                const unsigned* vp = (const unsigned*)&v;
#pragma unroll
                for (int q = 0; q < 4; ++q) {
                    pr[k * 8 + 2*q]     = bf16_lo(vp[q]);
                    pr[k * 8 + 2*q + 1] = bf16_hi(vp[q]);
                }
            }
            float* og = fout + sbase;
#pragma unroll
            for (int r = HALO; r < TDIM - HALO; ++r) {
                float e = (u[r] - ym) * inv;
                og[(size_t)(gy0 + r) * NN + col] =
                    __builtin_fmaf(rs, pr[r - HALO], e);   // coalesced: lanes = cols
            }
        }
    }
}

// ---------------------------------------------------------------------------
extern "C" void kernel_launch(void* const* d_in, const int* in_sizes, int n_in,
                              void* d_out, int out_size, void* d_ws, size_t ws_size,
                              hipStream_t stream)
{
    const float* x_mix  = (const float*)d_in[0];
    const float* w_back = (const float*)d_in[1];
    const float* b_back = (const float*)d_in[2];
    const float* logit  = (const float*)d_in[3];
    const float* y_mean = (const float*)d_in[4];
    const float* y_std  = (const float*)d_in[5];

    float* out = (float*)d_out;

    // Workspace (all transposed [b][col][row]):
    // [GUARD][u_a 2B][cm_t 1B][u_b 2B][pre_t 2B]
    // Halo reads stray <= ~8.3 KB past either end of u_a/cm_t/u_b; every such
    // access lands in an adjacent defined region or the guard (finite bf16).
    // pre_t reads/out writes are predicated strictly in-range.
    char* ws = (char*)d_ws;
    unsigned short* u_a   = (unsigned short*)(ws + GUARD);
    unsigned char*  cm_t  = (unsigned char*) (ws + GUARD + (size_t)TOTAL * 2);
    unsigned short* u_b   = (unsigned short*)(ws + GUARD + (size_t)TOTAL * 3);
    unsigned short* pre_t = (unsigned short*)(ws + GUARD + (size_t)TOTAL * 5);

    init_kernel<<<dim3(8, 8, BB), 256, 0, stream>>>(
        (const float4*)x_mix, u_a, cm_t, pre_t, w_back, b_back);

    // 50 iters = 6 launches x 8 + 1 launch x 2 (fused epilogue).
    // Chain: a->b, b->a, a->b, b->a, a->b, b->a, then FINAL a->out.
    const int nblk = (NTILES + 3) / 4;   // 484 blocks, 4 wave-tiles each
    wave_kernel<8, false><<<nblk, 256, 0, stream>>>(u_a, u_b, out, cm_t,
        pre_t, logit, y_mean, y_std);
    wave_kernel<8, false><<<nblk, 256, 0, stream>>>(u_b, u_a, out, cm_t,
        pre_t, logit, y_mean, y_std);
    wave_kernel<8, false><<<nblk, 256, 0, stream>>>(u_a, u_b, out, cm_t,
        pre_t, logit, y_mean, y_std);
    wave_kernel<8, false><<<nblk, 256, 0, stream>>>(u_b, u_a, out, cm_t,
        pre_t, logit, y_mean, y_std);
    wave_kernel<8, false><<<nblk, 256, 0, stream>>>(u_a, u_b, out, cm_t,
        pre_t, logit, y_mean, y_std);
    wave_kernel<8, false><<<nblk, 256, 0, stream>>>(u_b, u_a, out, cm_t,
        pre_t, logit, y_mean, y_std);
    wave_kernel<2, true><<<nblk, 256, 0, stream>>>(u_a, u_b, out, cm_t,
        pre_t, logit, y_mean, y_std);
}